// Round 1
// baseline (800.089 us; speedup 1.0000x reference)
//
#include <hip/hip_runtime.h>
#include <math.h>

// Problem constants
#define B 8
#define M 1024
#define D 768
#define NEXP 64
#define P 16
#define H 1536
#define S 1024          // n*p slots
#define EPS_NORM 1e-6f
#define EPS_LN   1e-5f

typedef unsigned short u16;
typedef __attribute__((ext_vector_type(8))) short bf16x8;
typedef __attribute__((ext_vector_type(4))) float f32x4;

__device__ __forceinline__ u16 f2bf(float f) {
    union { float f; unsigned u; } v; v.f = f;
    unsigned r = v.u + 0x7FFFu + ((v.u >> 16) & 1u);   // RNE
    return (u16)(r >> 16);
}

__device__ __forceinline__ float gelu_exact(float x) {
    return 0.5f * x * (1.0f + erff(x * 0.70710678118654752440f));
}

#define GLL16(g, l) __builtin_amdgcn_global_load_lds( \
    (const __attribute__((address_space(1))) void*)(g), \
    (__attribute__((address_space(3))) void*)(l), 16, 0, 0)

// ---------------------------------------------------------------------------
// MFMA GEMM core (NT, both operands bf16 k-contiguous): 128x128 tile, BK=32.
// Double-buffered: stage t+1 while computing t; ONE barrier per K-step.
// As/Bs are 2x4096 u16 (two 8 KB halves each).
__device__ __forceinline__ void mfma_core_128(const u16* __restrict__ Ag,
                                              const u16* __restrict__ Bg,
                                              int K, u16* As, u16* Bs,
                                              f32x4 (&acc)[4][4]) {
    const int t    = threadIdx.x;
    const int lane = t & 63;
    const int wave = t >> 6;
    const int wr   = (wave >> 1) << 6;
    const int wc   = (wave & 1) << 6;
    const int quad = lane >> 4;
    const int l16  = lane & 15;
    const u16* ga0 = Ag + (size_t)(t >> 2) * K + (t & 3) * 8;
    const u16* ga1 = ga0 + (size_t)64 * K;
    const u16* gb0 = Bg + (size_t)(t >> 2) * K + (t & 3) * 8;
    const u16* gb1 = gb0 + (size_t)64 * K;
    u16* la0 = As + t * 8;
    u16* lb0 = Bs + t * 8;
    const u16* arp = As + (wr + l16) * 32 + quad * 8;
    const u16* brp = Bs + (wc + l16) * 32 + quad * 8;
    // prologue: stage k0=0 into buffer 0
    GLL16(ga0, la0);
    GLL16(ga1, la0 + 2048);
    GLL16(gb0, lb0);
    GLL16(gb1, lb0 + 2048);
    int cur = 0;
    for (int k0 = 0; k0 < K; k0 += 32) {
        __syncthreads();                 // buf[cur] staged; prior-buf reads done
        const int nxt = cur ^ 1;
        if (k0 + 32 < K) {               // prefetch t+1 into buf[nxt]
            GLL16(ga0 + k0 + 32, la0 + nxt * 4096);
            GLL16(ga1 + k0 + 32, la0 + nxt * 4096 + 2048);
            GLL16(gb0 + k0 + 32, lb0 + nxt * 4096);
            GLL16(gb1 + k0 + 32, lb0 + nxt * 4096 + 2048);
        }
        const u16* ar = arp + cur * 4096;
        const u16* br = brp + cur * 4096;
        bf16x8 af[4], bfr[4];
#pragma unroll
        for (int i = 0; i < 4; ++i) af[i]  = *(const bf16x8*)(ar + i * 512);
#pragma unroll
        for (int j = 0; j < 4; ++j) bfr[j] = *(const bf16x8*)(br + j * 512);
#pragma unroll
        for (int i = 0; i < 4; ++i)
#pragma unroll
            for (int j = 0; j < 4; ++j)
                acc[i][j] = __builtin_amdgcn_mfma_f32_16x16x32_bf16(af[i], bfr[j], acc[i][j], 0, 0, 0);
        cur = nxt;
    }
}

// ---------------------------------------------------------------------------
// MFMA GEMM core, A bf16 NT (k-contig), B fp32 NATIVE k-major [K][ldb] read
// directly from global (weights). B is converted + transposed into LDS
// [col][k] (stride 40 u16). Double-buffered with T14 split staging:
// issue next-tile B loads early, cvt+write late (after the MFMA phase).
// As = 2x4096 u16, Bs = 2x5120 u16.
__device__ __forceinline__ void mfma_core_bf32(const u16* __restrict__ Ag, int K,
                                               const float* __restrict__ Bg, int ldb,
                                               u16* As, u16* Bs,
                                               f32x4 (&acc)[4][4]) {
    const int t    = threadIdx.x;
    const int lane = t & 63;
    const int wave = t >> 6;
    const int wr   = (wave >> 1) << 6;
    const int wc   = (wave & 1) << 6;
    const int quad = lane >> 4;
    const int l16  = lane & 15;
    const u16* ga0 = Ag + (size_t)(t >> 2) * K + (t & 3) * 8;
    const u16* ga1 = ga0 + (size_t)64 * K;
    u16* la0 = As + t * 8;
    const int bcol = t & 127;          // tile-local column
    const int kq   = (t >> 7) << 4;    // 0 or 16: k-group base
    const float* bg0 = Bg + (size_t)kq * ldb + bcol;
    u16* lb = Bs + bcol * 40 + kq;
    const u16* arp = As + (wr + l16) * 32 + quad * 8;
    const u16* brp = Bs + (wc + l16) * 40 + quad * 8;
    // prologue: stage step 0 into buffer 0 (latency exposed once)
    GLL16(ga0, la0);
    GLL16(ga1, la0 + 2048);
    {
        float f[16];
#pragma unroll
        for (int i = 0; i < 16; ++i) f[i] = bg0[(size_t)i * ldb];
#pragma unroll
        for (int i = 0; i < 4; ++i) {
            ushort4 o;
            o.x = f2bf(f[i*4 + 0]); o.y = f2bf(f[i*4 + 1]);
            o.z = f2bf(f[i*4 + 2]); o.w = f2bf(f[i*4 + 3]);
            *(ushort4*)(lb + i * 4) = o;
        }
    }
    int cur = 0;
    for (int k0 = 0; k0 < K; k0 += 32) {
        __syncthreads();                 // buf[cur] ready; prior-buf reads done
        const int nxt = cur ^ 1;
        const bool pf = (k0 + 32 < K);
        float f[16];
        if (pf) {
            // issue next-tile loads EARLY; results consumed after MFMA phase
            GLL16(ga0 + k0 + 32, la0 + nxt * 4096);
            GLL16(ga1 + k0 + 32, la0 + nxt * 4096 + 2048);
            const float* bg = bg0 + (size_t)(k0 + 32) * ldb;
#pragma unroll
            for (int i = 0; i < 16; ++i) f[i] = bg[(size_t)i * ldb];
        }
        // compute current buffer
        const u16* ar = arp + cur * 4096;
        const u16* br = brp + cur * 5120;
        bf16x8 af[4], bfr[4];
#pragma unroll
        for (int i = 0; i < 4; ++i) af[i]  = *(const bf16x8*)(ar + i * 512);
#pragma unroll
        for (int j = 0; j < 4; ++j) bfr[j] = *(const bf16x8*)(br + j * 640);
#pragma unroll
        for (int i = 0; i < 4; ++i)
#pragma unroll
            for (int j = 0; j < 4; ++j)
                acc[i][j] = __builtin_amdgcn_mfma_f32_16x16x32_bf16(af[i], bfr[j], acc[i][j], 0, 0, 0);
        if (pf) {
            // write-late: cvt + transpose-store into buf[nxt]
            u16* lbn = lb + nxt * 5120;
#pragma unroll
            for (int i = 0; i < 4; ++i) {
                ushort4 o;
                o.x = f2bf(f[i*4 + 0]); o.y = f2bf(f[i*4 + 1]);
                o.z = f2bf(f[i*4 + 2]); o.w = f2bf(f[i*4 + 3]);
                *(ushort4*)(lbn + i * 4) = o;
            }
        }
        cur = nxt;
    }
}

#define EPI_VARS \
    const int t = threadIdx.x; const int lane = t & 63; const int wave = t >> 6; \
    const int wr = (wave >> 1) << 6; const int wc = (wave & 1) << 6; \
    const int quad = lane >> 4; const int l16 = lane & 15; (void)t;

#define ACC_INIT \
    f32x4 acc[4][4]; \
    _Pragma("unroll") for (int i = 0; i < 4; ++i) \
    _Pragma("unroll") for (int j = 0; j < 4; ++j) acc[i][j] = (f32x4){0.f, 0.f, 0.f, 0.f};

// ---------------------------------------------------------------------------
// x prep: one read of x -> xb (bf16 [b][m][d]) + xT (bf16 [b][d][m])
__global__ __launch_bounds__(256) void xprep_kernel(const float* __restrict__ x,
                                                    u16* __restrict__ xb,
                                                    u16* __restrict__ xT) {
    __shared__ float tile[64][65];
    int b = blockIdx.z;
    int m0 = blockIdx.y * 64, d0 = blockIdx.x * 64;
    int tt = threadIdx.x;
    int rr = tt >> 4, c4 = (tt & 15) * 4;
#pragma unroll
    for (int i = 0; i < 4; ++i) {
        int m = m0 + rr + i * 16;
        float4 v = *(const float4*)(x + ((size_t)b * M + m) * D + d0 + c4);
        tile[rr + i*16][c4 + 0] = v.x;
        tile[rr + i*16][c4 + 1] = v.y;
        tile[rr + i*16][c4 + 2] = v.z;
        tile[rr + i*16][c4 + 3] = v.w;
        ushort4 o;
        o.x = f2bf(v.x); o.y = f2bf(v.y); o.z = f2bf(v.z); o.w = f2bf(v.w);
        *(ushort4*)(xb + ((size_t)b * M + m) * D + d0 + c4) = o;
    }
    __syncthreads();
    int cr = tt >> 4, r4 = (tt & 15) * 4;
#pragma unroll
    for (int i = 0; i < 4; ++i) {
        int crow = cr + i * 16;       // d index within tile
        ushort4 o;
        o.x = f2bf(tile[r4 + 0][crow]);
        o.y = f2bf(tile[r4 + 1][crow]);
        o.z = f2bf(tile[r4 + 2][crow]);
        o.w = f2bf(tile[r4 + 3][crow]);
        *(ushort4*)(xT + ((size_t)b * D + d0 + crow) * M + m0 + r4) = o;
    }
}

// phi_n = phi * rsqrt(sum_n phi^2 + eps), write bf16 [s][d]
__global__ __launch_bounds__(256) void phi_norm_kernel(const float* __restrict__ phi,
                                                       u16* __restrict__ phinb) {
    int pos = blockIdx.x * 256 + threadIdx.x;   // 0..P*D-1
    float ss = 0.f;
#pragma unroll 4
    for (int nn = 0; nn < NEXP; ++nn) {
        float v = phi[nn * (P*D) + pos];
        ss += v * v;
    }
    float r = rsqrtf(ss + EPS_NORM);
#pragma unroll 4
    for (int nn = 0; nn < NEXP; ++nn)
        phinb[nn * (P*D) + pos] = f2bf(phi[nn * (P*D) + pos] * r);
}

// ---------------------------------------------------------------------------
// GEMM kernels
// ---------------------------------------------------------------------------

// logits[b*m][s] = xb[b*m][d] . phinb[s][d]^T   (fp32 out)
__global__ __launch_bounds__(256) void gemm_logits_mfma(const u16* __restrict__ xb,
                                                        const u16* __restrict__ phinb,
                                                        float* __restrict__ logits) {
    __shared__ __align__(16) u16 As[8192], Bs[8192];
    ACC_INIT;
    const int row0 = blockIdx.y * 128, col0 = blockIdx.x * 128;
    mfma_core_128(xb + (size_t)row0 * D, phinb + (size_t)col0 * D, D, As, Bs, acc);
    EPI_VARS;
#pragma unroll
    for (int i = 0; i < 4; ++i)
#pragma unroll
        for (int j = 0; j < 4; ++j) {
            int col = col0 + wc + j*16 + l16;
#pragma unroll
            for (int r = 0; r < 4; ++r) {
                int row = row0 + wr + i*16 + quad*4 + r;
                logits[(size_t)row * S + col] = acc[i][j][r];
            }
        }
}

// Xs[b][s][d] = sum_m DT[b][s][m] * xT[b][d][m]   (fp32 out)
__global__ __launch_bounds__(256) void gemm_dispatch_mfma(const u16* __restrict__ DT,
                                                          const u16* __restrict__ xT,
                                                          float* __restrict__ Xs) {
    __shared__ __align__(16) u16 As[8192], Bs[8192];
    ACC_INIT;
    const int b = blockIdx.z;
    const int row0 = blockIdx.y * 128, col0 = blockIdx.x * 128;
    mfma_core_128(DT + ((size_t)b * S + row0) * M,
                  xT + ((size_t)b * D + col0) * M, M, As, Bs, acc);
    EPI_VARS;
#pragma unroll
    for (int i = 0; i < 4; ++i)
#pragma unroll
        for (int j = 0; j < 4; ++j) {
            int col = col0 + wc + j*16 + l16;
#pragma unroll
            for (int r = 0; r < 4; ++r) {
                int row = row0 + wr + i*16 + quad*4 + r;
                Xs[((size_t)b * S + row) * D + col] = acc[i][j][r];
            }
        }
}

// h1[n][r][h] = gelu(hdnE[n][r][:] . w1[n][:][h] + b1[n][h])  (bf16 out)
// B = w1 native [d][h] fp32, consumed directly (k-major).
__global__ __launch_bounds__(256) void gemm_mlp1_mfma(const u16* __restrict__ hdnE,
                                                      const float* __restrict__ w1,
                                                      const float* __restrict__ b1,
                                                      u16* __restrict__ h1) {
    __shared__ __align__(16) u16 As[8192], Bs[10240];
    ACC_INIT;
    const int n = blockIdx.z;
    const int col0 = blockIdx.x * 128;
    mfma_core_bf32(hdnE + (size_t)n * 128 * D, D,
                   w1 + (size_t)n * D * H + col0, H, As, Bs, acc);
    EPI_VARS;
#pragma unroll
    for (int i = 0; i < 4; ++i)
#pragma unroll
        for (int j = 0; j < 4; ++j) {
            int h = col0 + wc + j*16 + l16;
            float bias = b1[n * H + h];
#pragma unroll
            for (int r = 0; r < 4; ++r) {
                int row = wr + i*16 + quad*4 + r;
                h1[((size_t)n * 128 + row) * H + h] = f2bf(gelu_exact(acc[i][j][r] + bias));
            }
        }
}

// YsT[b][d][s] = h1[n][r][:] . w2[n][:][d] + b2[n][d]   (bf16 out, transposed scatter)
// B = w2 native [h][d] fp32, consumed directly (k-major).
__global__ __launch_bounds__(256) void gemm_mlp2_mfma(const u16* __restrict__ h1,
                                                      const float* __restrict__ w2,
                                                      const float* __restrict__ b2,
                                                      u16* __restrict__ YsT) {
    __shared__ __align__(16) u16 As[8192], Bs[10240];
    ACC_INIT;
    const int n = blockIdx.z;
    const int col0 = blockIdx.x * 128;
    mfma_core_bf32(h1 + (size_t)n * 128 * H, H,
                   w2 + (size_t)n * H * D + col0, D, As, Bs, acc);
    EPI_VARS;
#pragma unroll
    for (int i = 0; i < 4; ++i)
#pragma unroll
        for (int j = 0; j < 4; ++j) {
            int d = col0 + wc + j*16 + l16;
            float bias = b2[n * D + d];
            int bb = ((wr + i*16) >> 4);          // batch index 0..7
            int p0 = quad * 4;
            ushort4 o;
            o.x = f2bf(acc[i][j][0] + bias);
            o.y = f2bf(acc[i][j][1] + bias);
            o.z = f2bf(acc[i][j][2] + bias);
            o.w = f2bf(acc[i][j][3] + bias);
            *(ushort4*)(YsT + ((size_t)bb * D + d) * S + n * P + p0) = o;
        }
}

// out[b][m][d] = sum_s Cb[b][m][s] * YsT[b][d][s]   (fp32 out)
__global__ __launch_bounds__(256) void gemm_combine_mfma(const u16* __restrict__ Cb,
                                                         const u16* __restrict__ YsT,
                                                         float* __restrict__ out) {
    __shared__ __align__(16) u16 As[8192], Bs[8192];
    ACC_INIT;
    const int b = blockIdx.z;
    const int row0 = blockIdx.y * 128, col0 = blockIdx.x * 128;
    mfma_core_128(Cb + ((size_t)b * M + row0) * S,
                  YsT + ((size_t)b * D + col0) * S, S, As, Bs, acc);
    EPI_VARS;
#pragma unroll
    for (int i = 0; i < 4; ++i)
#pragma unroll
        for (int j = 0; j < 4; ++j) {
            int col = col0 + wc + j*16 + l16;
#pragma unroll
            for (int r = 0; r < 4; ++r) {
                int row = row0 + wr + i*16 + quad*4 + r;
                out[((size_t)b * M + row) * D + col] = acc[i][j][r];
            }
        }
}

// ---------------------------------------------------------------------------
// Softmax / LN kernels
// ---------------------------------------------------------------------------

__global__ __launch_bounds__(256) void softmax_row_kernel(const float* __restrict__ in,
                                                          u16* __restrict__ outb) {
    __shared__ float red[4], red2[4];
    int row = blockIdx.x;
    int t = threadIdx.x;
    const float* rp = in + (size_t)row * S;
    float4 v = *(const float4*)(rp + t*4);
    float mx = fmaxf(fmaxf(v.x, v.y), fmaxf(v.z, v.w));
#pragma unroll
    for (int o = 1; o < 64; o <<= 1) mx = fmaxf(mx, __shfl_xor(mx, o));
    if ((t & 63) == 0) red[t >> 6] = mx;
    __syncthreads();
    mx = fmaxf(fmaxf(red[0], red[1]), fmaxf(red[2], red[3]));
    float4 e;
    e.x = expf(v.x - mx); e.y = expf(v.y - mx); e.z = expf(v.z - mx); e.w = expf(v.w - mx);
    float sum = e.x + e.y + e.z + e.w;
#pragma unroll
    for (int o = 1; o < 64; o <<= 1) sum += __shfl_xor(sum, o);
    if ((t & 63) == 0) red2[t >> 6] = sum;
    __syncthreads();
    sum = red2[0] + red2[1] + red2[2] + red2[3];
    float inv = 1.f / sum;
    ushort4 o4;
    o4.x = f2bf(e.x * inv); o4.y = f2bf(e.y * inv);
    o4.z = f2bf(e.z * inv); o4.w = f2bf(e.w * inv);
    *(ushort4*)(outb + (size_t)row * S + t*4) = o4;
}

// 32 chunks of 32 rows each (was 8x128): 4x more waves to hide the serial
// online-softmax chain; grid 1024 blocks.
__global__ __launch_bounds__(256) void colsm_partial_kernel(const float* __restrict__ logits,
                                                            float* __restrict__ pm,
                                                            float* __restrict__ pl) {
    int gid = blockIdx.x * 256 + threadIdx.x;    // 0..262143
    int c   = gid >> 13;                         // 0..31
    int col = gid & 8191;                        // b*S + s
    int b = col >> 10, s = col & (S - 1);
    const float* base = logits + ((size_t)b << 20) + ((size_t)(c * 32) << 10) + s;
    float mx = -INFINITY, l = 0.f;
    for (int m = 0; m < 32; ++m) {
        float v = base[(size_t)m << 10];
        float nm = fmaxf(mx, v);
        l = l * expf(mx - nm) + expf(v - nm);
        mx = nm;
    }
    pm[gid] = mx;
    pl[gid] = l;
}

__global__ __launch_bounds__(256) void colsm_combine_kernel(const float* __restrict__ pm,
                                                            const float* __restrict__ pl,
                                                            float* __restrict__ fm,
                                                            float* __restrict__ fl) {
    int col = blockIdx.x * 256 + threadIdx.x;    // 0..8191
    float mx = -INFINITY;
#pragma unroll
    for (int c = 0; c < 32; ++c) mx = fmaxf(mx, pm[c * 8192 + col]);
    float l = 0.f;
#pragma unroll
    for (int c = 0; c < 32; ++c) l += pl[c * 8192 + col] * expf(pm[c * 8192 + col] - mx);
    fm[col] = mx;
    fl[col] = 1.f / l;
}

// normalize + transpose -> DT[b][s][m] bf16
__global__ __launch_bounds__(256) void dt_transpose_kernel(const float* __restrict__ logits,
                                                           const float* __restrict__ fm,
                                                           const float* __restrict__ fl,
                                                           u16* __restrict__ DT) {
    __shared__ float tile[64][65];
    int b = blockIdx.z;
    int m0 = blockIdx.y * 64, s0 = blockIdx.x * 64;
    int tt = threadIdx.x;
    int rr = tt >> 4, c4 = (tt & 15) * 4;
    float4 fmv = *(const float4*)(fm + (size_t)b * S + s0 + c4);
    float4 flv = *(const float4*)(fl + (size_t)b * S + s0 + c4);
#pragma unroll
    for (int i = 0; i < 4; ++i) {
        float4 v = *(const float4*)(logits + ((size_t)b * M + m0 + rr + i*16) * S + s0 + c4);
        tile[rr + i*16][c4 + 0] = expf(v.x - fmv.x) * flv.x;
        tile[rr + i*16][c4 + 1] = expf(v.y - fmv.y) * flv.y;
        tile[rr + i*16][c4 + 2] = expf(v.z - fmv.z) * flv.z;
        tile[rr + i*16][c4 + 3] = expf(v.w - fmv.w) * flv.w;
    }
    __syncthreads();
    int cr = tt >> 4, r4 = (tt & 15) * 4;
#pragma unroll
    for (int i = 0; i < 4; ++i) {
        int crow = cr + i * 16;       // s index within tile
        ushort4 o;
        o.x = f2bf(tile[r4 + 0][crow]);
        o.y = f2bf(tile[r4 + 1][crow]);
        o.z = f2bf(tile[r4 + 2][crow]);
        o.w = f2bf(tile[r4 + 3][crow]);
        *(ushort4*)(DT + ((size_t)b * S + s0 + crow) * M + m0 + r4) = o;
    }
}

// LayerNorm rows of Xs (fp32) -> hdnE bf16 in expert-major layout [n][b*16+p][d]
__global__ __launch_bounds__(256) void layernorm_kernel(const float* __restrict__ Xs,
                                                        const float* __restrict__ g,
                                                        const float* __restrict__ bt,
                                                        u16* __restrict__ hdnE) {
    __shared__ float rs[4], rq[4];
    int row = blockIdx.x;                  // b*1024 + n*16 + p
    int b = row >> 10;
    int n = (row >> 4) & (NEXP - 1);
    int p = row & 15;
    const float* rp = Xs + (size_t)row * D;
    u16* op = hdnE + ((size_t)n * 128 + b * 16 + p) * D;
    int t = threadIdx.x;
    float x0 = rp[t], x1 = rp[t + 256], x2 = rp[t + 512];
    float s  = x0 + x1 + x2;
    float sq = x0*x0 + x1*x1 + x2*x2;
#pragma unroll
    for (int o = 1; o < 64; o <<= 1) { s += __shfl_xor(s, o); sq += __shfl_xor(sq, o); }
    if ((t & 63) == 0) { rs[t >> 6] = s; rq[t >> 6] = sq; }
    __syncthreads();
    s  = rs[0] + rs[1] + rs[2] + rs[3];
    sq = rq[0] + rq[1] + rq[2] + rq[3];
    float mu  = s * (1.f / D);
    float var = sq * (1.f / D) - mu * mu;
    float inv = rsqrtf(var + EPS_LN);
    const float* gn = g  + n * D;
    const float* bn = bt + n * D;
    op[t]       = f2bf((x0 - mu) * inv * gn[t]       + bn[t]);
    op[t + 256] = f2bf((x1 - mu) * inv * gn[t + 256] + bn[t + 256]);
    op[t + 512] = f2bf((x2 - mu) * inv * gn[t + 512] + bn[t + 512]);
}

// ---------------------------------------------------------------------------
extern "C" void kernel_launch(void* const* d_in, const int* in_sizes, int n_in,
                              void* d_out, int out_size, void* d_ws, size_t ws_size,
                              hipStream_t stream) {
    const float* x    = (const float*)d_in[0];
    const float* phi  = (const float*)d_in[1];
    const float* ln_g = (const float*)d_in[2];
    const float* ln_b = (const float*)d_in[3];
    const float* w1   = (const float*)d_in[4];
    const float* b1   = (const float*)d_in[5];
    const float* w2   = (const float*)d_in[6];
    const float* b2   = (const float*)d_in[7];
    float* out = (float*)d_out;

    char* ws = (char*)d_ws;
    float* logits = (float*)(ws + 0);               // 33.6 MB (reused as Xs fp32)
    u16*   Cb     = (u16*)(ws + 33554432);          // 16.8 MB
    u16*   xb     = (u16*)(ws + 50331648);          // 12.6 MB (xb+DT reused as h1)
    u16*   DT     = (u16*)(ws + 62914560);          // 16.8 MB
    u16*   xTb    = (u16*)(ws + 79691776);          // 12.6 MB (reused as YsT)
    u16*   phinb  = (u16*)(ws + 92274688);          //  1.6 MB
    u16*   hdnE   = (u16*)(ws + 93847552);          // 12.6 MB
    float* pm     = (float*)(ws + 106430464);       //  1.0 MB (32 chunks)
    float* pl     = (float*)(ws + 107479040);       //  1.0 MB
    float* fm     = (float*)(ws + 108527616);
    float* fl     = (float*)(ws + 108560384);
    float* Xs     = logits;                         // overlay (logits dead by then)
    u16*   h1     = xb;                             // overlay (xb+DT dead by then)
    u16*   YsT    = xTb;                            // overlay (xTb dead by then)

    // --- operand preparation (single read of x; no weight prep) ---
    xprep_kernel<<<dim3(12, 16, B), 256, 0, stream>>>(x, xb, xTb);
    phi_norm_kernel<<<48, 256, 0, stream>>>(phi, phinb);

    // --- routing ---
    gemm_logits_mfma<<<dim3(8, 64), 256, 0, stream>>>(xb, phinb, logits);
    softmax_row_kernel<<<B * M, 256, 0, stream>>>(logits, Cb);
    colsm_partial_kernel<<<1024, 256, 0, stream>>>(logits, pm, pl);
    colsm_combine_kernel<<<32, 256, 0, stream>>>(pm, pl, fm, fl);
    dt_transpose_kernel<<<dim3(16, 16, B), 256, 0, stream>>>(logits, fm, fl, DT);

    // --- dispatch ---
    gemm_dispatch_mfma<<<dim3(6, 8, B), 256, 0, stream>>>(DT, xTb, Xs);
    layernorm_kernel<<<B * S, 256, 0, stream>>>(Xs, ln_g, ln_b, hdnE);

    // --- expert MLP (weights consumed directly from fp32 native layout) ---
    gemm_mlp1_mfma<<<dim3(12, 1, NEXP), 256, 0, stream>>>(hdnE, w1, b1, h1);
    gemm_mlp2_mfma<<<dim3(6, 1, NEXP), 256, 0, stream>>>(h1, w2, b2, YsT);

    // --- combine ---
    gemm_combine_mfma<<<dim3(6, 8, B), 256, 0, stream>>>(Cb, YsT, out);
}